// Round 1
// baseline (7173.094 us; speedup 1.0000x reference)
//
#include <hip/hip_runtime.h>
#include <hip/hip_bf16.h>
#include <math.h>

#define N_NODES 100000
#define N_EDGES 800000
#define H 256
#define NTYPES 22
#define BM 16
#define BK 32

// ---------------------------------------------------------------------------
// Small precompute: C1 = temp_W @ W1b (32x256), C2 = emb_table @ W1c (22x256),
// beff = fus_b1 + temp_b @ W1b (256)
// ---------------------------------------------------------------------------
__global__ __launch_bounds__(256) void prep_kernel(
    const float* __restrict__ temp_W, const float* __restrict__ temp_b,
    const float* __restrict__ emb, const float* __restrict__ fus_W1,
    const float* __restrict__ fus_b1,
    float* __restrict__ C1, float* __restrict__ C2, float* __restrict__ beff)
{
    int b = blockIdx.x;
    int j = threadIdx.x; // 0..255
    if (b < 32) {
        float acc = 0.f;
        #pragma unroll 8
        for (int m = 0; m < H; ++m)
            acc += temp_W[b * H + m] * fus_W1[(size_t)(H + m) * H + j];
        C1[b * H + j] = acc;
    } else if (b < 32 + NTYPES) {
        int e = b - 32;
        float acc = 0.f;
        #pragma unroll 8
        for (int m = 0; m < H; ++m)
            acc += emb[e * H + m] * fus_W1[(size_t)(2 * H + m) * H + j];
        C2[e * H + j] = acc;
    } else {
        float acc = fus_b1[j];
        #pragma unroll 8
        for (int m = 0; m < H; ++m)
            acc += temp_b[m] * fus_W1[(size_t)(H + m) * H + j];
        beff[j] = acc;
    }
}

// ---------------------------------------------------------------------------
// Edge degree count + reciprocal
// ---------------------------------------------------------------------------
__global__ void count_kernel(const int* __restrict__ dst, float* __restrict__ count)
{
    int e = blockIdx.x * blockDim.x + threadIdx.x;
    if (e < N_EDGES) atomicAdd(&count[dst[e]], 1.0f);
}

__global__ void invc_kernel(const float* __restrict__ count, float* __restrict__ invc)
{
    int i = blockIdx.x * blockDim.x + threadIdx.x;
    if (i < N_NODES) invc[i] = 1.0f / fmaxf(count[i], 1.0f);
}

// ---------------------------------------------------------------------------
// Scatter-add aggregation: one wave per edge, float4 per lane, 4 atomics
// ---------------------------------------------------------------------------
__global__ __launch_bounds__(256) void scatter_kernel(
    const float* __restrict__ x, const int* __restrict__ src,
    const int* __restrict__ dst, float* __restrict__ agg)
{
    int e = blockIdx.x * 4 + (threadIdx.x >> 6);
    int lane = threadIdx.x & 63;
    if (e >= N_EDGES) return;
    int s = src[e], d = dst[e];
    const float4 v = *reinterpret_cast<const float4*>(x + (size_t)s * H + lane * 4);
    float* ap = agg + (size_t)d * H + lane * 4;
    atomicAdd(ap + 0, v.x);
    atomicAdd(ap + 1, v.y);
    atomicAdd(ap + 2, v.z);
    atomicAdd(ap + 3, v.w);
}

// ---------------------------------------------------------------------------
// Shared GEMM tile helpers.
// Block: 256 threads; tx = tid&63 (column quad), ty = tid>>6 (row quad).
// Thread computes rows [ty*4, ty*4+4) x cols [tx*4, tx*4+4) of a BM x 256 tile.
// A wave (fixed ty) owns 4 full rows -> LN is a pure wave reduction.
// ---------------------------------------------------------------------------
__device__ __forceinline__ void stage_A(float (*As)[BK], const float* Asrc, int tid)
{
    if (tid < 128) {
        int r = tid >> 3, kq = (tid & 7) << 2;
        *reinterpret_cast<float4*>(&As[r][kq]) =
            *reinterpret_cast<const float4*>(Asrc + (size_t)r * H + kq);
    }
}

__device__ __forceinline__ void stage_A_scaled(float (*As)[BK], const float* Asrc,
                                               const float* invs, int tid)
{
    if (tid < 128) {
        int r = tid >> 3, kq = (tid & 7) << 2;
        float4 v = *reinterpret_cast<const float4*>(Asrc + (size_t)r * H + kq);
        float s = invs[r];
        v.x *= s; v.y *= s; v.z *= s; v.w *= s;
        *reinterpret_cast<float4*>(&As[r][kq]) = v;
    }
}

__device__ __forceinline__ void stage_B(float (*Bs)[H], const float* Bsrc, int tid)
{
    #pragma unroll
    for (int rep = 0; rep < 8; ++rep) {
        int idx = rep * 256 + tid;
        int kr = idx >> 6, c4 = (idx & 63) << 2;
        *reinterpret_cast<float4*>(&Bs[kr][c4]) =
            *reinterpret_cast<const float4*>(Bsrc + (size_t)kr * H + c4);
    }
}

__device__ __forceinline__ void tile_mac(const float (*As)[BK], const float (*Bs)[H],
                                         int ty, int tx, float acc[4][4])
{
    #pragma unroll
    for (int kk = 0; kk < BK; kk += 4) {
        float4 av[4];
        #pragma unroll
        for (int r = 0; r < 4; ++r)
            av[r] = *reinterpret_cast<const float4*>(&As[ty * 4 + r][kk]);
        float4 bv0 = *reinterpret_cast<const float4*>(&Bs[kk + 0][tx * 4]);
        float4 bv1 = *reinterpret_cast<const float4*>(&Bs[kk + 1][tx * 4]);
        float4 bv2 = *reinterpret_cast<const float4*>(&Bs[kk + 2][tx * 4]);
        float4 bv3 = *reinterpret_cast<const float4*>(&Bs[kk + 3][tx * 4]);
        #pragma unroll
        for (int r = 0; r < 4; ++r) {
            const float a0 = av[r].x, a1 = av[r].y, a2 = av[r].z, a3 = av[r].w;
            acc[r][0] += a0 * bv0.x + a1 * bv1.x + a2 * bv2.x + a3 * bv3.x;
            acc[r][1] += a0 * bv0.y + a1 * bv1.y + a2 * bv2.y + a3 * bv3.y;
            acc[r][2] += a0 * bv0.z + a1 * bv1.z + a2 * bv2.z + a3 * bv3.z;
            acc[r][3] += a0 * bv0.w + a1 * bv1.w + a2 * bv2.w + a3 * bv3.w;
        }
    }
}

// ---------------------------------------------------------------------------
// K1: fused temporal-encode + GEMM1 + relu.  h (=> d_out) = relu(pre)
// pre = clause@W1a + pe@C1 + C2[type] + beff
// ---------------------------------------------------------------------------
__global__ __launch_bounds__(256) void k1_encode_gemm1(
    const float* __restrict__ clause, const float* __restrict__ ts,
    const int* __restrict__ types, const float* __restrict__ fus_W1,
    const float* __restrict__ C1, const float* __restrict__ C2,
    const float* __restrict__ beff, float* __restrict__ h)
{
    __shared__ float As[BM][BK];
    __shared__ float Bs[BK][H];
    int tid = threadIdx.x;
    int tx = tid & 63, ty = tid >> 6;
    int i0 = blockIdx.x * BM;
    float acc[4][4] = {};

    for (int t = 0; t < 8; ++t) {
        stage_A(As, clause + (size_t)i0 * H + t * BK, tid);
        stage_B(Bs, fus_W1 + (size_t)t * BK * H, tid);
        __syncthreads();
        tile_mac(As, Bs, ty, tx, acc);
        __syncthreads();
    }
    // temporal-encoding tile: pe (16 x 32) into As, C1 as B
    {
        #pragma unroll
        for (int v = 0; v < 2; ++v) {
            int idx = v * 256 + tid;
            int r = idx >> 5, k = idx & 31;
            float tsv = ts[i0 + r];
            float fr = expf((float)(k & 15) * -0.57564627324851f); // -ln(1e4)/16
            float ang = tsv * fr;
            As[r][k] = (k < 16) ? sinf(ang) : cosf(ang);
        }
        stage_B(Bs, C1, tid);
        __syncthreads();
        tile_mac(As, Bs, ty, tx, acc);
    }
    // epilogue: + beff + C2[type], relu, store
    int j0 = tx << 2;
    float4 be = *reinterpret_cast<const float4*>(beff + j0);
    #pragma unroll
    for (int r = 0; r < 4; ++r) {
        int row = i0 + ty * 4 + r;
        int tp = types[row];
        float4 c2 = *reinterpret_cast<const float4*>(C2 + (size_t)tp * H + j0);
        float4 o;
        o.x = fmaxf(acc[r][0] + be.x + c2.x, 0.f);
        o.y = fmaxf(acc[r][1] + be.y + c2.y, 0.f);
        o.z = fmaxf(acc[r][2] + be.z + c2.z, 0.f);
        o.w = fmaxf(acc[r][3] + be.w + c2.w, 0.f);
        *reinterpret_cast<float4*>(h + (size_t)row * H + j0) = o;
    }
}

// ---------------------------------------------------------------------------
// K2: x = LN(h@fus_W2 + fus_b2 + clause) * in_g + in_b      (in-place: h==x)
// ---------------------------------------------------------------------------
__global__ __launch_bounds__(256) void k2_gemm2_ln(
    float* x, const float* __restrict__ fus_W2,
    const float* __restrict__ fus_b2, const float* __restrict__ clause,
    const float* __restrict__ in_g, const float* __restrict__ in_b)
{
    __shared__ float As[BM][BK];
    __shared__ float Bs[BK][H];
    int tid = threadIdx.x;
    int tx = tid & 63, ty = tid >> 6;
    int i0 = blockIdx.x * BM;
    float acc[4][4] = {};

    for (int t = 0; t < 8; ++t) {
        stage_A(As, x + (size_t)i0 * H + t * BK, tid);
        stage_B(Bs, fus_W2 + (size_t)t * BK * H, tid);
        __syncthreads();
        tile_mac(As, Bs, ty, tx, acc);
        __syncthreads();
    }
    int j0 = tx << 2;
    float4 b2 = *reinterpret_cast<const float4*>(fus_b2 + j0);
    float4 g4 = *reinterpret_cast<const float4*>(in_g + j0);
    float4 bb = *reinterpret_cast<const float4*>(in_b + j0);
    #pragma unroll
    for (int r = 0; r < 4; ++r) {
        int row = i0 + ty * 4 + r;
        float4 cl = *reinterpret_cast<const float4*>(clause + (size_t)row * H + j0);
        float p0 = acc[r][0] + b2.x + cl.x;
        float p1 = acc[r][1] + b2.y + cl.y;
        float p2 = acc[r][2] + b2.z + cl.z;
        float p3 = acc[r][3] + b2.w + cl.w;
        float s = p0 + p1 + p2 + p3;
        float q = p0 * p0 + p1 * p1 + p2 * p2 + p3 * p3;
        #pragma unroll
        for (int off = 32; off > 0; off >>= 1) {
            s += __shfl_xor(s, off);
            q += __shfl_xor(q, off);
        }
        float mu = s * (1.0f / 256.0f);
        float rstd = rsqrtf(q * (1.0f / 256.0f) - mu * mu + 1e-5f);
        float4 o;
        o.x = (p0 - mu) * rstd * g4.x + bb.x;
        o.y = (p1 - mu) * rstd * g4.y + bb.y;
        o.z = (p2 - mu) * rstd * g4.z + bb.z;
        o.w = (p3 - mu) * rstd * g4.w + bb.w;
        *reinterpret_cast<float4*>(x + (size_t)row * H + j0) = o;
    }
}

// ---------------------------------------------------------------------------
// K5: one message-passing layer.
// x = LN(x + relu([x | agg*invc] @ Wl + bl), gl, bnl)       (in-place x)
// ---------------------------------------------------------------------------
__global__ __launch_bounds__(256) void k5_mp_gemm_ln(
    float* x, const float* __restrict__ agg, const float* __restrict__ invc,
    const float* __restrict__ Wl, const float* __restrict__ bl,
    const float* __restrict__ gl, const float* __restrict__ bnl)
{
    __shared__ float As[BM][BK];
    __shared__ float Bs[BK][H];
    __shared__ float invs[BM];
    int tid = threadIdx.x;
    int tx = tid & 63, ty = tid >> 6;
    int i0 = blockIdx.x * BM;
    float acc[4][4] = {};

    if (tid < BM) invs[tid] = invc[i0 + tid];

    for (int t = 0; t < 16; ++t) {
        if (t < 8)
            stage_A(As, x + (size_t)i0 * H + t * BK, tid);
        else
            stage_A_scaled(As, agg + (size_t)i0 * H + (t - 8) * BK, invs, tid);
        stage_B(Bs, Wl + (size_t)t * BK * H, tid);
        __syncthreads();
        tile_mac(As, Bs, ty, tx, acc);
        __syncthreads();
    }
    int j0 = tx << 2;
    float4 bl4 = *reinterpret_cast<const float4*>(bl + j0);
    float4 g4 = *reinterpret_cast<const float4*>(gl + j0);
    float4 bb = *reinterpret_cast<const float4*>(bnl + j0);
    #pragma unroll
    for (int r = 0; r < 4; ++r) {
        int row = i0 + ty * 4 + r;
        float4 xo = *reinterpret_cast<const float4*>(x + (size_t)row * H + j0);
        float p0 = xo.x + fmaxf(acc[r][0] + bl4.x, 0.f);
        float p1 = xo.y + fmaxf(acc[r][1] + bl4.y, 0.f);
        float p2 = xo.z + fmaxf(acc[r][2] + bl4.z, 0.f);
        float p3 = xo.w + fmaxf(acc[r][3] + bl4.w, 0.f);
        float s = p0 + p1 + p2 + p3;
        float q = p0 * p0 + p1 * p1 + p2 * p2 + p3 * p3;
        #pragma unroll
        for (int off = 32; off > 0; off >>= 1) {
            s += __shfl_xor(s, off);
            q += __shfl_xor(q, off);
        }
        float mu = s * (1.0f / 256.0f);
        float rstd = rsqrtf(q * (1.0f / 256.0f) - mu * mu + 1e-5f);
        float4 o;
        o.x = (p0 - mu) * rstd * g4.x + bb.x;
        o.y = (p1 - mu) * rstd * g4.y + bb.y;
        o.z = (p2 - mu) * rstd * g4.z + bb.z;
        o.w = (p3 - mu) * rstd * g4.w + bb.w;
        *reinterpret_cast<float4*>(x + (size_t)row * H + j0) = o;
    }
}

// ---------------------------------------------------------------------------
extern "C" void kernel_launch(void* const* d_in, const int* in_sizes, int n_in,
                              void* d_out, int out_size, void* d_ws, size_t ws_size,
                              hipStream_t stream)
{
    const float* clause  = (const float*)d_in[0];
    const float* ts      = (const float*)d_in[1];
    const int*   types   = (const int*)  d_in[2];
    const int*   edges   = (const int*)  d_in[3];
    const float* emb     = (const float*)d_in[4];
    const float* temp_W  = (const float*)d_in[5];
    const float* temp_b  = (const float*)d_in[6];
    const float* fus_W1  = (const float*)d_in[7];
    const float* fus_b1  = (const float*)d_in[8];
    const float* fus_W2  = (const float*)d_in[9];
    const float* fus_b2  = (const float*)d_in[10];
    const float* in_g    = (const float*)d_in[11];
    const float* in_b    = (const float*)d_in[12];
    const float* deriv_W = (const float*)d_in[13];
    const float* deriv_b = (const float*)d_in[14];
    const float* dn_g    = (const float*)d_in[15];
    const float* dn_b    = (const float*)d_in[16];

    float* C1    = (float*)d_ws;                 // 32*256
    float* C2    = C1 + 32 * H;                  // 22*256
    float* beff  = C2 + NTYPES * H;              // 256
    float* count = beff + H;                     // N
    float* invc  = count + N_NODES;              // N
    float* agg   = invc + N_NODES;               // N*256
    float* x     = (float*)d_out;

    const int* src = edges;
    const int* dst = edges + N_EDGES;

    prep_kernel<<<32 + NTYPES + 1, 256, 0, stream>>>(temp_W, temp_b, emb, fus_W1,
                                                     fus_b1, C1, C2, beff);
    hipMemsetAsync(count, 0, N_NODES * sizeof(float), stream);
    count_kernel<<<(N_EDGES + 255) / 256, 256, 0, stream>>>(dst, count);
    invc_kernel<<<(N_NODES + 255) / 256, 256, 0, stream>>>(count, invc);

    k1_encode_gemm1<<<N_NODES / BM, 256, 0, stream>>>(clause, ts, types, fus_W1,
                                                      C1, C2, beff, x);
    k2_gemm2_ln<<<N_NODES / BM, 256, 0, stream>>>(x, fus_W2, fus_b2, clause,
                                                  in_g, in_b);

    for (int l = 0; l < 2; ++l) {
        hipMemsetAsync(agg, 0, (size_t)N_NODES * H * sizeof(float), stream);
        scatter_kernel<<<N_EDGES / 4, 256, 0, stream>>>(x, src, dst, agg);
        k5_mp_gemm_ln<<<N_NODES / BM, 256, 0, stream>>>(
            x, agg, invc, deriv_W + (size_t)l * 2 * H * H,
            deriv_b + (size_t)l * H, dn_g + (size_t)l * H, dn_b + (size_t)l * H);
    }
}

// Round 2
// 3031.506 us; speedup vs baseline: 2.3662x; 2.3662x over previous
//
#include <hip/hip_runtime.h>
#include <hip/hip_bf16.h>
#include <math.h>

#define N_NODES 100000
#define N_EDGES 800000
#define H 256
#define NTYPES 22
#define BM 16
#define BK 32
#define SCAN_G 98   // ceil(100000/1024)

// ---------------------------------------------------------------------------
// Small precompute: C1 = temp_W @ W1b (32x256), C2 = emb_table @ W1c (22x256),
// beff = fus_b1 + temp_b @ W1b (256)
// ---------------------------------------------------------------------------
__global__ __launch_bounds__(256) void prep_kernel(
    const float* __restrict__ temp_W, const float* __restrict__ temp_b,
    const float* __restrict__ emb, const float* __restrict__ fus_W1,
    const float* __restrict__ fus_b1,
    float* __restrict__ C1, float* __restrict__ C2, float* __restrict__ beff)
{
    int b = blockIdx.x;
    int j = threadIdx.x; // 0..255
    if (b < 32) {
        float acc = 0.f;
        #pragma unroll 8
        for (int m = 0; m < H; ++m)
            acc += temp_W[b * H + m] * fus_W1[(size_t)(H + m) * H + j];
        C1[b * H + j] = acc;
    } else if (b < 32 + NTYPES) {
        int e = b - 32;
        float acc = 0.f;
        #pragma unroll 8
        for (int m = 0; m < H; ++m)
            acc += emb[e * H + m] * fus_W1[(size_t)(2 * H + m) * H + j];
        C2[e * H + j] = acc;
    } else {
        float acc = fus_b1[j];
        #pragma unroll 8
        for (int m = 0; m < H; ++m)
            acc += temp_b[m] * fus_W1[(size_t)(H + m) * H + j];
        beff[j] = acc;
    }
}

// ---------------------------------------------------------------------------
// CSR build: count -> block scan -> fill
// ---------------------------------------------------------------------------
__global__ void count_kernel(const int* __restrict__ dst, int* __restrict__ cnt)
{
    int e = blockIdx.x * blockDim.x + threadIdx.x;
    if (e < N_EDGES) atomicAdd(&cnt[dst[e]], 1);
}

__global__ __launch_bounds__(1024) void scan1_kernel(
    const int* __restrict__ cnt, int* __restrict__ off, int* __restrict__ bsum)
{
    __shared__ int s[1024];
    int i = blockIdx.x * 1024 + threadIdx.x;
    int v = (i < N_NODES) ? cnt[i] : 0;
    s[threadIdx.x] = v;
    __syncthreads();
    #pragma unroll
    for (int o = 1; o < 1024; o <<= 1) {
        int t = (threadIdx.x >= o) ? s[threadIdx.x - o] : 0;
        __syncthreads();
        s[threadIdx.x] += t;
        __syncthreads();
    }
    if (i < N_NODES) off[i] = s[threadIdx.x];          // per-block inclusive
    if (threadIdx.x == 1023) bsum[blockIdx.x] = s[1023];
}

__global__ void scan2_kernel(const int* __restrict__ bsum, int* __restrict__ bbase)
{
    if (threadIdx.x == 0) {
        int acc = 0;
        for (int b = 0; b < SCAN_G; ++b) { bbase[b] = acc; acc += bsum[b]; }
    }
}

__global__ __launch_bounds__(1024) void scan3_kernel(
    int* __restrict__ off, const int* __restrict__ bbase,
    const int* __restrict__ cnt, int* __restrict__ cursor)
{
    int i = blockIdx.x * 1024 + threadIdx.x;
    if (i < N_NODES) {
        int incl = off[i] + bbase[blockIdx.x];
        off[i] = incl;                  // global inclusive scan
        cursor[i] = incl - cnt[i];      // bucket start
    }
}

__global__ void fill_kernel(const int* __restrict__ src, const int* __restrict__ dst,
                            int* __restrict__ cursor, int* __restrict__ csr)
{
    int e = blockIdx.x * blockDim.x + threadIdx.x;
    if (e < N_EDGES) {
        int pos = atomicAdd(&cursor[dst[e]], 1);
        csr[pos] = src[e];
    }
}

// ---------------------------------------------------------------------------
// Shared GEMM tile helpers.
// Block: 256 threads; tx = tid&63 (column quad), ty = tid>>6 (row quad).
// Thread computes rows [ty*4, ty*4+4) x cols [tx*4, tx*4+4) of a BM x 256 tile.
// A wave (fixed ty) owns 4 full rows -> LN is a pure wave reduction.
// ---------------------------------------------------------------------------
__device__ __forceinline__ void stage_A(float (*As)[BK], const float* Asrc, int tid)
{
    if (tid < 128) {
        int r = tid >> 3, kq = (tid & 7) << 2;
        *reinterpret_cast<float4*>(&As[r][kq]) =
            *reinterpret_cast<const float4*>(Asrc + (size_t)r * H + kq);
    }
}

__device__ __forceinline__ void stage_B(float (*Bs)[H], const float* Bsrc, int tid)
{
    #pragma unroll
    for (int rep = 0; rep < 8; ++rep) {
        int idx = rep * 256 + tid;
        int kr = idx >> 6, c4 = (idx & 63) << 2;
        *reinterpret_cast<float4*>(&Bs[kr][c4]) =
            *reinterpret_cast<const float4*>(Bsrc + (size_t)kr * H + c4);
    }
}

// A is a pointer with runtime leading dim (LDS: either As (lda=BK) or Agg (lda=H))
__device__ __forceinline__ void tile_mac(const float* A, int lda, const float (*Bs)[H],
                                         int ty, int tx, float acc[4][4])
{
    #pragma unroll
    for (int kk = 0; kk < BK; kk += 4) {
        float4 av[4];
        #pragma unroll
        for (int r = 0; r < 4; ++r)
            av[r] = *reinterpret_cast<const float4*>(A + (ty * 4 + r) * lda + kk);
        float4 bv0 = *reinterpret_cast<const float4*>(&Bs[kk + 0][tx * 4]);
        float4 bv1 = *reinterpret_cast<const float4*>(&Bs[kk + 1][tx * 4]);
        float4 bv2 = *reinterpret_cast<const float4*>(&Bs[kk + 2][tx * 4]);
        float4 bv3 = *reinterpret_cast<const float4*>(&Bs[kk + 3][tx * 4]);
        #pragma unroll
        for (int r = 0; r < 4; ++r) {
            const float a0 = av[r].x, a1 = av[r].y, a2 = av[r].z, a3 = av[r].w;
            acc[r][0] += a0 * bv0.x + a1 * bv1.x + a2 * bv2.x + a3 * bv3.x;
            acc[r][1] += a0 * bv0.y + a1 * bv1.y + a2 * bv2.y + a3 * bv3.y;
            acc[r][2] += a0 * bv0.z + a1 * bv1.z + a2 * bv2.z + a3 * bv3.z;
            acc[r][3] += a0 * bv0.w + a1 * bv1.w + a2 * bv2.w + a3 * bv3.w;
        }
    }
}

// ---------------------------------------------------------------------------
// K1: fused temporal-encode + GEMM1 + relu.  h (=> d_out) = relu(pre)
// pre = clause@W1a + pe@C1 + C2[type] + beff
// ---------------------------------------------------------------------------
__global__ __launch_bounds__(256) void k1_encode_gemm1(
    const float* __restrict__ clause, const float* __restrict__ ts,
    const int* __restrict__ types, const float* __restrict__ fus_W1,
    const float* __restrict__ C1, const float* __restrict__ C2,
    const float* __restrict__ beff, float* __restrict__ h)
{
    __shared__ float As[BM][BK];
    __shared__ float Bs[BK][H];
    int tid = threadIdx.x;
    int tx = tid & 63, ty = tid >> 6;
    int i0 = blockIdx.x * BM;
    float acc[4][4] = {};

    for (int t = 0; t < 8; ++t) {
        stage_A(As, clause + (size_t)i0 * H + t * BK, tid);
        stage_B(Bs, fus_W1 + (size_t)t * BK * H, tid);
        __syncthreads();
        tile_mac(&As[0][0], BK, Bs, ty, tx, acc);
        __syncthreads();
    }
    // temporal-encoding tile: pe (16 x 32) into As, C1 as B
    {
        #pragma unroll
        for (int v = 0; v < 2; ++v) {
            int idx = v * 256 + tid;
            int r = idx >> 5, k = idx & 31;
            float tsv = ts[i0 + r];
            float fr = expf((float)(k & 15) * -0.57564627324851f); // -ln(1e4)/16
            float ang = tsv * fr;
            As[r][k] = (k < 16) ? sinf(ang) : cosf(ang);
        }
        stage_B(Bs, C1, tid);
        __syncthreads();
        tile_mac(&As[0][0], BK, Bs, ty, tx, acc);
    }
    // epilogue: + beff + C2[type], relu, store
    int j0 = tx << 2;
    float4 be = *reinterpret_cast<const float4*>(beff + j0);
    #pragma unroll
    for (int r = 0; r < 4; ++r) {
        int row = i0 + ty * 4 + r;
        int tp = types[row];
        float4 c2 = *reinterpret_cast<const float4*>(C2 + (size_t)tp * H + j0);
        float4 o;
        o.x = fmaxf(acc[r][0] + be.x + c2.x, 0.f);
        o.y = fmaxf(acc[r][1] + be.y + c2.y, 0.f);
        o.z = fmaxf(acc[r][2] + be.z + c2.z, 0.f);
        o.w = fmaxf(acc[r][3] + be.w + c2.w, 0.f);
        *reinterpret_cast<float4*>(h + (size_t)row * H + j0) = o;
    }
}

// ---------------------------------------------------------------------------
// K2: x = LN(h@fus_W2 + fus_b2 + clause) * in_g + in_b      (in-place: h==x)
// ---------------------------------------------------------------------------
__global__ __launch_bounds__(256) void k2_gemm2_ln(
    float* x, const float* __restrict__ fus_W2,
    const float* __restrict__ fus_b2, const float* __restrict__ clause,
    const float* __restrict__ in_g, const float* __restrict__ in_b)
{
    __shared__ float As[BM][BK];
    __shared__ float Bs[BK][H];
    int tid = threadIdx.x;
    int tx = tid & 63, ty = tid >> 6;
    int i0 = blockIdx.x * BM;
    float acc[4][4] = {};

    for (int t = 0; t < 8; ++t) {
        stage_A(As, x + (size_t)i0 * H + t * BK, tid);
        stage_B(Bs, fus_W2 + (size_t)t * BK * H, tid);
        __syncthreads();
        tile_mac(&As[0][0], BK, Bs, ty, tx, acc);
        __syncthreads();
    }
    int j0 = tx << 2;
    float4 b2 = *reinterpret_cast<const float4*>(fus_b2 + j0);
    float4 g4 = *reinterpret_cast<const float4*>(in_g + j0);
    float4 bb = *reinterpret_cast<const float4*>(in_b + j0);
    #pragma unroll
    for (int r = 0; r < 4; ++r) {
        int row = i0 + ty * 4 + r;
        float4 cl = *reinterpret_cast<const float4*>(clause + (size_t)row * H + j0);
        float p0 = acc[r][0] + b2.x + cl.x;
        float p1 = acc[r][1] + b2.y + cl.y;
        float p2 = acc[r][2] + b2.z + cl.z;
        float p3 = acc[r][3] + b2.w + cl.w;
        float s = p0 + p1 + p2 + p3;
        float q = p0 * p0 + p1 * p1 + p2 * p2 + p3 * p3;
        #pragma unroll
        for (int off = 32; off > 0; off >>= 1) {
            s += __shfl_xor(s, off);
            q += __shfl_xor(q, off);
        }
        float mu = s * (1.0f / 256.0f);
        float rstd = rsqrtf(q * (1.0f / 256.0f) - mu * mu + 1e-5f);
        float4 o;
        o.x = (p0 - mu) * rstd * g4.x + bb.x;
        o.y = (p1 - mu) * rstd * g4.y + bb.y;
        o.z = (p2 - mu) * rstd * g4.z + bb.z;
        o.w = (p3 - mu) * rstd * g4.w + bb.w;
        *reinterpret_cast<float4*>(x + (size_t)row * H + j0) = o;
    }
}

// ---------------------------------------------------------------------------
// K5: one message-passing layer, with FUSED CSR-gather aggregation.
// xout = LN(xin + relu([xin | mean_{src->i} xin[src]] @ Wl + bl), gl, bnl)
// Out-of-place (xin != xout) to avoid cross-block RAW on the gather.
// ---------------------------------------------------------------------------
__global__ __launch_bounds__(256) void k5_mp_gemm_ln(
    const float* __restrict__ xin, float* __restrict__ xout,
    const int* __restrict__ csr, const int* __restrict__ off,
    const int* __restrict__ cnt,
    const float* __restrict__ Wl, const float* __restrict__ bl,
    const float* __restrict__ gl, const float* __restrict__ bnl)
{
    __shared__ float As[BM][BK];
    __shared__ float Bs[BK][H];
    __shared__ float Agg[BM][H];
    int tid = threadIdx.x;
    int tx = tid & 63, ty = tid >> 6;
    int lane = tx, wid = ty;
    int i0 = blockIdx.x * BM;

    // --- gather prologue: wave wid computes mean of parent rows for 4 nodes ---
    #pragma unroll
    for (int i = 0; i < 4; ++i) {
        int r = wid * 4 + i;
        int node = i0 + r;
        int deg = cnt[node];
        int start = off[node] - deg;
        float4 a = {0.f, 0.f, 0.f, 0.f};
        for (int j = 0; j < deg; ++j) {
            int s = csr[start + j];
            float4 v = *reinterpret_cast<const float4*>(xin + (size_t)s * H + lane * 4);
            a.x += v.x; a.y += v.y; a.z += v.z; a.w += v.w;
        }
        float sc = 1.0f / fmaxf((float)deg, 1.0f);
        a.x *= sc; a.y *= sc; a.z *= sc; a.w *= sc;
        *reinterpret_cast<float4*>(&Agg[r][lane * 4]) = a;
    }
    // Agg consumed only at t>=8; the t=0 __syncthreads() covers the hazard.

    float acc[4][4] = {};
    for (int t = 0; t < 16; ++t) {
        if (t < 8)
            stage_A(As, xin + (size_t)i0 * H + t * BK, tid);
        stage_B(Bs, Wl + (size_t)t * BK * H, tid);
        __syncthreads();
        if (t < 8)
            tile_mac(&As[0][0], BK, Bs, ty, tx, acc);
        else
            tile_mac(&Agg[0][(t - 8) * BK], H, Bs, ty, tx, acc);
        __syncthreads();
    }

    int j0 = tx << 2;
    float4 bl4 = *reinterpret_cast<const float4*>(bl + j0);
    float4 g4 = *reinterpret_cast<const float4*>(gl + j0);
    float4 bb = *reinterpret_cast<const float4*>(bnl + j0);
    #pragma unroll
    for (int r = 0; r < 4; ++r) {
        int row = i0 + ty * 4 + r;
        float4 xo = *reinterpret_cast<const float4*>(xin + (size_t)row * H + j0);
        float p0 = xo.x + fmaxf(acc[r][0] + bl4.x, 0.f);
        float p1 = xo.y + fmaxf(acc[r][1] + bl4.y, 0.f);
        float p2 = xo.z + fmaxf(acc[r][2] + bl4.z, 0.f);
        float p3 = xo.w + fmaxf(acc[r][3] + bl4.w, 0.f);
        float s = p0 + p1 + p2 + p3;
        float q = p0 * p0 + p1 * p1 + p2 * p2 + p3 * p3;
        #pragma unroll
        for (int o2 = 32; o2 > 0; o2 >>= 1) {
            s += __shfl_xor(s, o2);
            q += __shfl_xor(q, o2);
        }
        float mu = s * (1.0f / 256.0f);
        float rstd = rsqrtf(q * (1.0f / 256.0f) - mu * mu + 1e-5f);
        float4 o;
        o.x = (p0 - mu) * rstd * g4.x + bb.x;
        o.y = (p1 - mu) * rstd * g4.y + bb.y;
        o.z = (p2 - mu) * rstd * g4.z + bb.z;
        o.w = (p3 - mu) * rstd * g4.w + bb.w;
        *reinterpret_cast<float4*>(xout + (size_t)row * H + j0) = o;
    }
}

// ---------------------------------------------------------------------------
extern "C" void kernel_launch(void* const* d_in, const int* in_sizes, int n_in,
                              void* d_out, int out_size, void* d_ws, size_t ws_size,
                              hipStream_t stream)
{
    const float* clause  = (const float*)d_in[0];
    const float* ts      = (const float*)d_in[1];
    const int*   types   = (const int*)  d_in[2];
    const int*   edges   = (const int*)  d_in[3];
    const float* emb     = (const float*)d_in[4];
    const float* temp_W  = (const float*)d_in[5];
    const float* temp_b  = (const float*)d_in[6];
    const float* fus_W1  = (const float*)d_in[7];
    const float* fus_b1  = (const float*)d_in[8];
    const float* fus_W2  = (const float*)d_in[9];
    const float* fus_b2  = (const float*)d_in[10];
    const float* in_g    = (const float*)d_in[11];
    const float* in_b    = (const float*)d_in[12];
    const float* deriv_W = (const float*)d_in[13];
    const float* deriv_b = (const float*)d_in[14];
    const float* dn_g    = (const float*)d_in[15];
    const float* dn_b    = (const float*)d_in[16];

    float* C1   = (float*)d_ws;              // 32*256
    float* C2   = C1 + 32 * H;               // 22*256
    float* beff = C2 + NTYPES * H;           // 256
    int* cnt    = (int*)(beff + H);          // N
    int* off    = cnt + N_NODES;             // N
    int* cursor = off + N_NODES;             // N
    int* bsum   = cursor + N_NODES;          // 128
    int* bbase  = bsum + 128;                // 128
    int* csr    = bbase + 128;               // E
    float* xb   = (float*)(csr + N_EDGES);   // N*H ping-pong buffer
    float* x    = (float*)d_out;

    const int* src = edges;
    const int* dst = edges + N_EDGES;

    prep_kernel<<<32 + NTYPES + 1, 256, 0, stream>>>(temp_W, temp_b, emb, fus_W1,
                                                     fus_b1, C1, C2, beff);
    hipMemsetAsync(cnt, 0, N_NODES * sizeof(int), stream);
    count_kernel<<<(N_EDGES + 255) / 256, 256, 0, stream>>>(dst, cnt);
    scan1_kernel<<<SCAN_G, 1024, 0, stream>>>(cnt, off, bsum);
    scan2_kernel<<<1, 64, 0, stream>>>(bsum, bbase);
    scan3_kernel<<<SCAN_G, 1024, 0, stream>>>(off, bbase, cnt, cursor);
    fill_kernel<<<(N_EDGES + 255) / 256, 256, 0, stream>>>(src, dst, cursor, csr);

    k1_encode_gemm1<<<N_NODES / BM, 256, 0, stream>>>(clause, ts, types, fus_W1,
                                                      C1, C2, beff, x);
    k2_gemm2_ln<<<N_NODES / BM, 256, 0, stream>>>(x, fus_W2, fus_b2, clause,
                                                  in_g, in_b);

    // layer 0: x -> xb ; layer 1: xb -> x
    k5_mp_gemm_ln<<<N_NODES / BM, 256, 0, stream>>>(
        x, xb, csr, off, cnt, deriv_W, deriv_b, dn_g, dn_b);
    k5_mp_gemm_ln<<<N_NODES / BM, 256, 0, stream>>>(
        xb, x, csr, off, cnt, deriv_W + (size_t)2 * H * H,
        deriv_b + H, dn_g + H, dn_b + H);
}

// Round 3
// 546.422 us; speedup vs baseline: 13.1274x; 5.5479x over previous
//
#include <hip/hip_runtime.h>
#include <hip/hip_bf16.h>
#include <math.h>

#define N_NODES 100000
#define N_EDGES 800000
#define H 256
#define NTYPES 22
#define SCAN_G 98                       // ceil(100000/1024)
#define GRID_G ((N_NODES + 63) / 64)    // 1563 blocks of BM=64

typedef __attribute__((ext_vector_type(8))) short short8;
typedef __attribute__((ext_vector_type(4))) float f32x4;
typedef unsigned short u16;

__device__ __forceinline__ u16 f2bf(float f) {
    unsigned u = __float_as_uint(f);
    u += 0x7FFF + ((u >> 16) & 1);      // RNE
    return (u16)(u >> 16);
}
__device__ __forceinline__ float bf2f(u16 u) {
    return __uint_as_float(((unsigned)u) << 16);
}

// ---------------------------------------------------------------------------
// prep_small: C1 = temp_W @ W1b (32x256) fp32, C2 = emb @ W1c (22x256) fp32,
// beff = fus_b1 + temp_b @ W1b (256) fp32
// ---------------------------------------------------------------------------
__global__ __launch_bounds__(256) void prep_small(
    const float* __restrict__ temp_W, const float* __restrict__ temp_b,
    const float* __restrict__ emb, const float* __restrict__ fus_W1,
    const float* __restrict__ fus_b1,
    float* __restrict__ C1, float* __restrict__ C2, float* __restrict__ beff)
{
    int b = blockIdx.x;
    int j = threadIdx.x;
    if (b < 32) {
        float acc = 0.f;
        #pragma unroll 8
        for (int m = 0; m < H; ++m)
            acc += temp_W[b * H + m] * fus_W1[(size_t)(H + m) * H + j];
        C1[b * H + j] = acc;
    } else if (b < 32 + NTYPES) {
        int e = b - 32;
        float acc = 0.f;
        #pragma unroll 8
        for (int m = 0; m < H; ++m)
            acc += emb[e * H + m] * fus_W1[(size_t)(2 * H + m) * H + j];
        C2[e * H + j] = acc;
    } else {
        float acc = fus_b1[j];
        #pragma unroll 8
        for (int m = 0; m < H; ++m)
            acc += temp_b[m] * fus_W1[(size_t)(H + m) * H + j];
        beff[j] = acc;
    }
}

// ---------------------------------------------------------------------------
// prep_frag: pack weights into MFMA B-fragment order, bf16.
// Blob layout: kstep s (49 total) x chunk c (1024) x 8 bf16.
// chunk c: ntile = c>>6, l = c&63 -> col n = ntile*16 + (l&15),
//          k_in_step = 8*(l>>4) + i.
// s 0..7: fus_W1 rows 0..255 (clause part), s==8: C1 (32 rows),
// s 9..16: fus_W2, s 17..32: deriv_W[0], s 33..48: deriv_W[1].
// ---------------------------------------------------------------------------
__global__ __launch_bounds__(256) void prep_frag(
    const float* __restrict__ fus_W1, const float* __restrict__ C1,
    const float* __restrict__ fus_W2, const float* __restrict__ deriv_W,
    u16* __restrict__ wblob)
{
    int s = blockIdx.x;
    const float* src; int kbase;
    if (s < 8)       { src = fus_W1;              kbase = s * 32; }
    else if (s == 8) { src = C1;                  kbase = 0; }
    else if (s < 17) { src = fus_W2;              kbase = (s - 9) * 32; }
    else if (s < 33) { src = deriv_W;             kbase = (s - 17) * 32; }
    else             { src = deriv_W + 512 * H;   kbase = (s - 33) * 32; }
    #pragma unroll
    for (int it = 0; it < 4; ++it) {
        int c = it * 256 + threadIdx.x;
        int l = c & 63, nt = c >> 6;
        int n = (nt << 4) | (l & 15);
        int k0 = kbase + ((l >> 4) << 3);
        short8 v;
        #pragma unroll
        for (int i = 0; i < 8; ++i)
            v[i] = (short)f2bf(src[(size_t)(k0 + i) * H + n]);
        *reinterpret_cast<short8*>(wblob + (size_t)s * 8192 + (size_t)c * 8) = v;
    }
}

// ---------------------------------------------------------------------------
// CSR build (unchanged from round 1)
// ---------------------------------------------------------------------------
__global__ void count_kernel(const int* __restrict__ dst, int* __restrict__ cnt)
{
    int e = blockIdx.x * blockDim.x + threadIdx.x;
    if (e < N_EDGES) atomicAdd(&cnt[dst[e]], 1);
}

__global__ __launch_bounds__(1024) void scan1_kernel(
    const int* __restrict__ cnt, int* __restrict__ off, int* __restrict__ bsum)
{
    __shared__ int s[1024];
    int i = blockIdx.x * 1024 + threadIdx.x;
    int v = (i < N_NODES) ? cnt[i] : 0;
    s[threadIdx.x] = v;
    __syncthreads();
    #pragma unroll
    for (int o = 1; o < 1024; o <<= 1) {
        int t = (threadIdx.x >= o) ? s[threadIdx.x - o] : 0;
        __syncthreads();
        s[threadIdx.x] += t;
        __syncthreads();
    }
    if (i < N_NODES) off[i] = s[threadIdx.x];
    if (threadIdx.x == 1023) bsum[blockIdx.x] = s[1023];
}

__global__ void scan2_kernel(const int* __restrict__ bsum, int* __restrict__ bbase)
{
    if (threadIdx.x == 0) {
        int acc = 0;
        for (int b = 0; b < SCAN_G; ++b) { bbase[b] = acc; acc += bsum[b]; }
    }
}

__global__ __launch_bounds__(1024) void scan3_kernel(
    int* __restrict__ off, const int* __restrict__ bbase,
    const int* __restrict__ cnt, int* __restrict__ cursor)
{
    int i = blockIdx.x * 1024 + threadIdx.x;
    if (i < N_NODES) {
        int incl = off[i] + bbase[blockIdx.x];
        off[i] = incl;
        cursor[i] = incl - cnt[i];
    }
}

__global__ void fill_kernel(const int* __restrict__ src, const int* __restrict__ dst,
                            int* __restrict__ cursor, int* __restrict__ csr)
{
    int e = blockIdx.x * blockDim.x + threadIdx.x;
    if (e < N_EDGES) {
        int pos = atomicAdd(&cursor[dst[e]], 1);
        csr[pos] = src[e];
    }
}

// ---------------------------------------------------------------------------
// gather_kernel: one wave per node; mean of parent rows (bf16 in, bf16 out).
// High occupancy (no LDS, few VGPR) hides the random-row latency.
// ---------------------------------------------------------------------------
__global__ __launch_bounds__(256) void gather_kernel(
    const u16* __restrict__ xb, const int* __restrict__ csr,
    const int* __restrict__ off, const int* __restrict__ cnt,
    u16* __restrict__ agg)
{
    int node = blockIdx.x * 4 + (threadIdx.x >> 6);
    int l = threadIdx.x & 63;
    int deg = cnt[node];
    int start = off[node] - deg;
    float a0 = 0.f, a1 = 0.f, a2 = 0.f, a3 = 0.f;
    float b0 = 0.f, b1 = 0.f, b2 = 0.f, b3 = 0.f;
    int j = 0;
    for (; j + 1 < deg; j += 2) {
        int s0 = csr[start + j], s1 = csr[start + j + 1];
        ushort4 v0 = *reinterpret_cast<const ushort4*>(xb + (size_t)s0 * H + l * 4);
        ushort4 v1 = *reinterpret_cast<const ushort4*>(xb + (size_t)s1 * H + l * 4);
        a0 += bf2f(v0.x); a1 += bf2f(v0.y); a2 += bf2f(v0.z); a3 += bf2f(v0.w);
        b0 += bf2f(v1.x); b1 += bf2f(v1.y); b2 += bf2f(v1.z); b3 += bf2f(v1.w);
    }
    if (j < deg) {
        int s0 = csr[start + j];
        ushort4 v0 = *reinterpret_cast<const ushort4*>(xb + (size_t)s0 * H + l * 4);
        a0 += bf2f(v0.x); a1 += bf2f(v0.y); a2 += bf2f(v0.z); a3 += bf2f(v0.w);
    }
    float sc = 1.0f / fmaxf((float)deg, 1.0f);
    ushort4 o;
    o.x = f2bf((a0 + b0) * sc); o.y = f2bf((a1 + b1) * sc);
    o.z = f2bf((a2 + b2) * sc); o.w = f2bf((a3 + b3) * sc);
    *reinterpret_cast<ushort4*>(agg + (size_t)node * H + l * 4) = o;
}

// ---------------------------------------------------------------------------
// MFMA GEMM core helpers (BM=64, 256 threads = 4 waves, wave w owns cols
// [64w, 64w+64)). Fragment-order LDS; all ds accesses are b128 conflict-free.
// ---------------------------------------------------------------------------
__device__ __forceinline__ void stageA_bf16(u16* Af, const u16* __restrict__ src,
                                            int i0, int kbase, int tid)
{
    int w = tid >> 6, l = tid & 63;
    int row = i0 + ((w << 4) | (l & 15));
    row = min(row, N_NODES - 1);
    const u16* p = src + (size_t)row * H + kbase + ((l >> 4) << 3);
    short8 v = *reinterpret_cast<const short8*>(p);
    *reinterpret_cast<short8*>(Af + (size_t)((w << 6) | l) * 8) = v;
}

__device__ __forceinline__ void stageA_f32(u16* Af, const float* __restrict__ src,
                                           int i0, int kbase, int tid)
{
    int w = tid >> 6, l = tid & 63;
    int row = i0 + ((w << 4) | (l & 15));
    row = min(row, N_NODES - 1);
    const float* p = src + (size_t)row * H + kbase + ((l >> 4) << 3);
    float4 a = *reinterpret_cast<const float4*>(p);
    float4 b = *reinterpret_cast<const float4*>(p + 4);
    short8 v;
    v[0] = (short)f2bf(a.x); v[1] = (short)f2bf(a.y);
    v[2] = (short)f2bf(a.z); v[3] = (short)f2bf(a.w);
    v[4] = (short)f2bf(b.x); v[5] = (short)f2bf(b.y);
    v[6] = (short)f2bf(b.z); v[7] = (short)f2bf(b.w);
    *reinterpret_cast<short8*>(Af + (size_t)((w << 6) | l) * 8) = v;
}

__device__ __forceinline__ void stageB(u16* Bf, const u16* __restrict__ wk, int tid)
{
    #pragma unroll
    for (int it = 0; it < 4; ++it) {
        int c = (it << 8) + tid;
        short8 v = *reinterpret_cast<const short8*>(wk + (size_t)c * 8);
        *reinterpret_cast<short8*>(Bf + (size_t)c * 8) = v;
    }
}

__device__ __forceinline__ void mfma_step(const u16* Af, const u16* Bf,
                                          int w, int l, f32x4 acc[4][4])
{
    short8 a[4];
    #pragma unroll
    for (int m = 0; m < 4; ++m)
        a[m] = *reinterpret_cast<const short8*>(Af + (size_t)((m << 6) | l) * 8);
    #pragma unroll
    for (int n = 0; n < 4; ++n) {
        short8 b = *reinterpret_cast<const short8*>(
            Bf + (size_t)((((w << 2) | n) << 6) | l) * 8);
        #pragma unroll
        for (int m = 0; m < 4; ++m)
            acc[m][n] = __builtin_amdgcn_mfma_f32_16x16x32_bf16(a[m], b, acc[m][n],
                                                                0, 0, 0);
    }
}

// ---------------------------------------------------------------------------
// K1: h(bf16) = relu(clause@W1a + pe@C1 + C2[type] + beff)
// ---------------------------------------------------------------------------
__global__ __launch_bounds__(256, 3) void k1_mfma(
    const float* __restrict__ clause, const float* __restrict__ ts,
    const int* __restrict__ types, const u16* __restrict__ wblob,
    const float* __restrict__ C2, const float* __restrict__ beff,
    u16* __restrict__ hb)
{
    __shared__ __align__(16) u16 Af[2048];
    __shared__ __align__(16) u16 Bf[8192];
    int tid = threadIdx.x, w = tid >> 6, l = tid & 63;
    int i0 = blockIdx.x * 64;
    f32x4 acc[4][4] = {};

    for (int t = 0; t < 9; ++t) {
        if (t < 8) {
            stageA_f32(Af, clause, i0, t * 32, tid);
        } else {
            // temporal pe tile: row rl = 16w + (l&15), k = 8*(l>>4)+i
            int rl = (w << 4) | (l & 15);
            int row = min(i0 + rl, N_NODES - 1);
            float tsv = ts[row];
            int g = l >> 4;
            short8 v;
            #pragma unroll
            for (int i = 0; i < 8; ++i) {
                int k = (g << 3) + i;
                float fr = expf(-0.57564627324851f * (float)(k & 15));
                float ang = tsv * fr;
                float pv = (k < 16) ? sinf(ang) : cosf(ang);
                v[i] = (short)f2bf(pv);
            }
            *reinterpret_cast<short8*>(Af + (size_t)((w << 6) | l) * 8) = v;
        }
        stageB(Bf, wblob + (size_t)t * 8192, tid);
        __syncthreads();
        mfma_step(Af, Bf, w, l, acc);
        __syncthreads();
    }

    int g = l >> 4, c0 = l & 15;
    float be[4];
    #pragma unroll
    for (int n = 0; n < 4; ++n) be[n] = beff[(w << 6) | (n << 4) | c0];
    #pragma unroll
    for (int m = 0; m < 4; ++m) {
        #pragma unroll
        for (int r = 0; r < 4; ++r) {
            int row = i0 + (m << 4) + (g << 2) + r;
            bool ok = row < N_NODES;
            int tp = types[ok ? row : 0];
            const float* c2r = C2 + (size_t)tp * H;
            #pragma unroll
            for (int n = 0; n < 4; ++n) {
                int col = (w << 6) | (n << 4) | c0;
                float val = fmaxf(acc[m][n][r] + be[n] + c2r[col], 0.f);
                if (ok) hb[(size_t)row * H + col] = f2bf(val);
            }
        }
    }
}

// ---------------------------------------------------------------------------
// K2: x = LN(h@W2 + b2 + clause)*g + b ; writes x fp32 (d_out) + x bf16
// (in-place over hb — safe: stage reads drain before epilogue writes)
// ---------------------------------------------------------------------------
__global__ __launch_bounds__(256, 3) void k2_mfma(
    const u16* __restrict__ hb, const u16* __restrict__ wblob,
    const float* __restrict__ b2, const float* __restrict__ clause,
    const float* __restrict__ gW, const float* __restrict__ bW,
    float* __restrict__ xo, u16* __restrict__ xb)
{
    __shared__ __align__(16) u16 Af[2048];
    __shared__ __align__(16) u16 Bf[8192];
    __shared__ float2 red[256];
    int tid = threadIdx.x, w = tid >> 6, l = tid & 63;
    int i0 = blockIdx.x * 64;
    f32x4 acc[4][4] = {};

    for (int t = 0; t < 8; ++t) {
        stageA_bf16(Af, hb, i0, t * 32, tid);
        stageB(Bf, wblob + (size_t)t * 8192, tid);
        __syncthreads();
        mfma_step(Af, Bf, w, l, acc);
        __syncthreads();
    }

    int g = l >> 4, c0 = l & 15;
    float bv[4], gv[4], bbv[4];
    #pragma unroll
    for (int n = 0; n < 4; ++n) {
        int col = (w << 6) | (n << 4) | c0;
        bv[n] = b2[col]; gv[n] = gW[col]; bbv[n] = bW[col];
    }
    #pragma unroll
    for (int m = 0; m < 4; ++m) {
        #pragma unroll
        for (int r = 0; r < 4; ++r) {
            int row = i0 + (m << 4) + (g << 2) + r;
            int rowc = min(row, N_NODES - 1);
            const float* cr = clause + (size_t)rowc * H;
            float s = 0.f, q = 0.f;
            #pragma unroll
            for (int n = 0; n < 4; ++n) {
                float pv = acc[m][n][r] + bv[n] + cr[(w << 6) | (n << 4) | c0];
                acc[m][n][r] = pv;
                s += pv; q += pv * pv;
            }
            #pragma unroll
            for (int o = 1; o < 16; o <<= 1) {
                s += __shfl_xor(s, o);
                q += __shfl_xor(q, o);
            }
            if (c0 == 0)
                red[((m << 4) + (g << 2) + r) * 4 + w] = make_float2(s, q);
        }
    }
    __syncthreads();
    #pragma unroll
    for (int m = 0; m < 4; ++m) {
        #pragma unroll
        for (int r = 0; r < 4; ++r) {
            int rl = (m << 4) + (g << 2) + r;
            int row = i0 + rl;
            float2 t0 = red[rl * 4 + 0], t1 = red[rl * 4 + 1];
            float2 t2 = red[rl * 4 + 2], t3 = red[rl * 4 + 3];
            float S = t0.x + t1.x + t2.x + t3.x;
            float Q = t0.y + t1.y + t2.y + t3.y;
            float mu = S * (1.0f / 256.0f);
            float rstd = rsqrtf(Q * (1.0f / 256.0f) - mu * mu + 1e-5f);
            if (row < N_NODES) {
                #pragma unroll
                for (int n = 0; n < 4; ++n) {
                    int col = (w << 6) | (n << 4) | c0;
                    float val = (acc[m][n][r] - mu) * rstd * gv[n] + bbv[n];
                    xo[(size_t)row * H + col] = val;
                    xb[(size_t)row * H + col] = f2bf(val);
                }
            }
        }
    }
}

// ---------------------------------------------------------------------------
// K5: x = LN(x + relu([x|agg]@Wl + bl))*g + b ; A from bf16 x/agg,
// residual fp32 in-place; optional bf16 shadow write for next layer.
// ---------------------------------------------------------------------------
template<bool WB16>
__global__ __launch_bounds__(256, 3) void k5_mfma(
    const u16* __restrict__ xb, const u16* __restrict__ aggb,
    float* __restrict__ x, const u16* __restrict__ wblob,
    const float* __restrict__ bl, const float* __restrict__ gl,
    const float* __restrict__ bnl, u16* __restrict__ xbout)
{
    __shared__ __align__(16) u16 Af[2048];
    __shared__ __align__(16) u16 Bf[8192];
    __shared__ float2 red[256];
    int tid = threadIdx.x, w = tid >> 6, l = tid & 63;
    int i0 = blockIdx.x * 64;
    f32x4 acc[4][4] = {};

    for (int t = 0; t < 16; ++t) {
        const u16* src = (t < 8) ? xb : aggb;
        stageA_bf16(Af, src, i0, (t & 7) * 32, tid);
        stageB(Bf, wblob + (size_t)t * 8192, tid);
        __syncthreads();
        mfma_step(Af, Bf, w, l, acc);
        __syncthreads();
    }

    int g = l >> 4, c0 = l & 15;
    float bv[4], gv[4], bbv[4];
    #pragma unroll
    for (int n = 0; n < 4; ++n) {
        int col = (w << 6) | (n << 4) | c0;
        bv[n] = bl[col]; gv[n] = gl[col]; bbv[n] = bnl[col];
    }
    #pragma unroll
    for (int m = 0; m < 4; ++m) {
        #pragma unroll
        for (int r = 0; r < 4; ++r) {
            int row = i0 + (m << 4) + (g << 2) + r;
            int rowc = min(row, N_NODES - 1);
            const float* xr = x + (size_t)rowc * H;
            float s = 0.f, q = 0.f;
            #pragma unroll
            for (int n = 0; n < 4; ++n) {
                float pv = xr[(w << 6) | (n << 4) | c0]
                         + fmaxf(acc[m][n][r] + bv[n], 0.f);
                acc[m][n][r] = pv;
                s += pv; q += pv * pv;
            }
            #pragma unroll
            for (int o = 1; o < 16; o <<= 1) {
                s += __shfl_xor(s, o);
                q += __shfl_xor(q, o);
            }
            if (c0 == 0)
                red[((m << 4) + (g << 2) + r) * 4 + w] = make_float2(s, q);
        }
    }
    __syncthreads();
    #pragma unroll
    for (int m = 0; m < 4; ++m) {
        #pragma unroll
        for (int r = 0; r < 4; ++r) {
            int rl = (m << 4) + (g << 2) + r;
            int row = i0 + rl;
            float2 t0 = red[rl * 4 + 0], t1 = red[rl * 4 + 1];
            float2 t2 = red[rl * 4 + 2], t3 = red[rl * 4 + 3];
            float S = t0.x + t1.x + t2.x + t3.x;
            float Q = t0.y + t1.y + t2.y + t3.y;
            float mu = S * (1.0f / 256.0f);
            float rstd = rsqrtf(Q * (1.0f / 256.0f) - mu * mu + 1e-5f);
            if (row < N_NODES) {
                #pragma unroll
                for (int n = 0; n < 4; ++n) {
                    int col = (w << 6) | (n << 4) | c0;
                    float val = (acc[m][n][r] - mu) * rstd * gv[n] + bbv[n];
                    x[(size_t)row * H + col] = val;
                    if (WB16) xbout[(size_t)row * H + col] = f2bf(val);
                }
            }
        }
    }
}

// ---------------------------------------------------------------------------
extern "C" void kernel_launch(void* const* d_in, const int* in_sizes, int n_in,
                              void* d_out, int out_size, void* d_ws, size_t ws_size,
                              hipStream_t stream)
{
    const float* clause  = (const float*)d_in[0];
    const float* ts      = (const float*)d_in[1];
    const int*   types   = (const int*)  d_in[2];
    const int*   edges   = (const int*)  d_in[3];
    const float* emb     = (const float*)d_in[4];
    const float* temp_W  = (const float*)d_in[5];
    const float* temp_b  = (const float*)d_in[6];
    const float* fus_W1  = (const float*)d_in[7];
    const float* fus_b1  = (const float*)d_in[8];
    const float* fus_W2  = (const float*)d_in[9];
    const float* fus_b2  = (const float*)d_in[10];
    const float* in_g    = (const float*)d_in[11];
    const float* in_b    = (const float*)d_in[12];
    const float* deriv_W = (const float*)d_in[13];
    const float* deriv_b = (const float*)d_in[14];
    const float* dn_g    = (const float*)d_in[15];
    const float* dn_b    = (const float*)d_in[16];

    char* p = (char*)d_ws;
    float* C1   = (float*)p;            p += 32 * H * 4;
    float* C2   = (float*)p;            p += NTYPES * H * 4;
    float* beff = (float*)p;            p += H * 4;
    int* cnt    = (int*)p;              p += N_NODES * 4;
    int* off    = (int*)p;              p += N_NODES * 4;
    int* cursor = (int*)p;              p += N_NODES * 4;
    int* bsum   = (int*)p;              p += 128 * 4;
    int* bbase  = (int*)p;              p += 128 * 4;
    int* csr    = (int*)p;              p += N_EDGES * 4;
    u16* wblob  = (u16*)p;              p += 49 * 8192 * 2;
    u16* xb16   = (u16*)p;              p += (size_t)N_NODES * H * 2;
    u16* aggb16 = (u16*)p;              p += (size_t)N_NODES * H * 2;
    float* x    = (float*)d_out;

    const int* src = edges;
    const int* dst = edges + N_EDGES;

    prep_small<<<32 + NTYPES + 1, 256, 0, stream>>>(temp_W, temp_b, emb, fus_W1,
                                                    fus_b1, C1, C2, beff);
    prep_frag<<<49, 256, 0, stream>>>(fus_W1, C1, fus_W2, deriv_W, wblob);

    hipMemsetAsync(cnt, 0, N_NODES * sizeof(int), stream);
    count_kernel<<<(N_EDGES + 255) / 256, 256, 0, stream>>>(dst, cnt);
    scan1_kernel<<<SCAN_G, 1024, 0, stream>>>(cnt, off, bsum);
    scan2_kernel<<<1, 64, 0, stream>>>(bsum, bbase);
    scan3_kernel<<<SCAN_G, 1024, 0, stream>>>(off, bbase, cnt, cursor);
    fill_kernel<<<(N_EDGES + 255) / 256, 256, 0, stream>>>(src, dst, cursor, csr);

    k1_mfma<<<GRID_G, 256, 0, stream>>>(clause, ts, types, wblob, C2, beff, xb16);
    k2_mfma<<<GRID_G, 256, 0, stream>>>(xb16, wblob + (size_t)9 * 8192, fus_b2,
                                        clause, in_g, in_b, x, xb16);

    // layer 0
    gather_kernel<<<N_NODES / 4, 256, 0, stream>>>(xb16, csr, off, cnt, aggb16);
    k5_mfma<true><<<GRID_G, 256, 0, stream>>>(
        xb16, aggb16, x, wblob + (size_t)17 * 8192,
        deriv_b, dn_g, dn_b, xb16);
    // layer 1
    gather_kernel<<<N_NODES / 4, 256, 0, stream>>>(xb16, csr, off, cnt, aggb16);
    k5_mfma<false><<<GRID_G, 256, 0, stream>>>(
        xb16, aggb16, x, wblob + (size_t)33 * 8192,
        deriv_b + H, dn_g + H, dn_b + H, nullptr);
}